// Round 8
// baseline (608.204 us; speedup 1.0000x reference)
//
#include <hip/hip_runtime.h>
#include <hip/hip_cooperative_groups.h>

namespace cg = cooperative_groups;

#define NREL 3
#define NB    64            // buckets per push-list
#define CS    16            // ints per bucket counter (64 B line each)
#define CAP0  131072        // nodes needing h0  (expected ~45K)
#define CAP1  32768         // nodes needing h1  (expected ~15K)
#define CAPE1 65536         // layer-1 relevant edges (expected ~30K)
#define CAPE2 16384         // layer-2 relevant edges (expected ~10K)
#define BC0   (CAP0 / NB)   // 2048 (shift 11)
#define BC1   (CAP1 / NB)   // 512  (shift 9)
#define BCE1  (CAPE1 / NB)  // 1024 (shift 10)
#define BCE2  (CAPE2 / NB)  // 256  (shift 8)
#define CTR(list, b) ((list) * NB * CS + (b) * CS)
#define SMEM_F 13312        // 53248 B LDS arena -> 2-3 blocks/CU

struct Params {
    const int *x, *src, *dst, *et, *ptr;
    const float *se, *ce, *pw, *pb;
    const float *w1r, *w1rt, *b1;
    const float *w2r, *w2rt, *b2;
    const float *cw, *cb;
    float *out;
    int nN, nE, G, nBW;
    int *ctr;
    unsigned *bitL, *bitN1;
    float *cntc, *aggm1, *aggm2;
    int *inv_map, *slot1, *slot0, *elist1, *elist2, *nodes1, *nodes0;
    float *h0c, *h1c;
};

__device__ __forceinline__ int bittest(const unsigned* bm, int n) {
    return (bm[n >> 5] >> (n & 31)) & 1u;
}

__device__ __forceinline__ void claim_node(int n, int* __restrict__ slot,
                                           int* __restrict__ nodes,
                                           int* __restrict__ ctr, int list,
                                           int bcap, int bucket) {
    if (atomicCAS(&slot[n], -1, -2) == -1) {
        int p = atomicAdd(&ctr[CTR(list, bucket)], 1);
        if (p < bcap) {
            int sl = bucket * bcap + p;
            nodes[sl] = n;                 // read only after grid.sync()
            atomicExch(&slot[n], sl);
        }
    }
}

__global__ __launch_bounds__(256, 2) void fused_k(Params P) {
    cg::grid_group grid = cg::this_grid();
    __shared__ float smem[SMEM_F];
    const int t   = threadIdx.x;
    const int tid = blockIdx.x * blockDim.x + t;
    const int nT  = gridDim.x * blockDim.x;

    // ================= phase 0: init workspace =================
    {
        int4 m1 = make_int4(-1, -1, -1, -1);
        int n4 = P.nN >> 2;
        int4* s0 = (int4*)P.slot0; int4* s1 = (int4*)P.slot1; int4* im = (int4*)P.inv_map;
        for (int i = tid; i < n4; i += nT) { s0[i] = m1; s1[i] = m1; im[i] = m1; }
        for (int i = (n4 << 2) + tid; i < P.nN; i += nT) {
            P.slot0[i] = -1; P.slot1[i] = -1; P.inv_map[i] = -1;
        }
        for (int i = tid; i < P.nBW; i += nT) { P.bitL[i] = 0u; P.bitN1[i] = 0u; }
        for (int i = tid; i < 4 * NB * CS; i += nT) P.ctr[i] = 0;
        float4 zf = make_float4(0.f, 0.f, 0.f, 0.f);
        float4* c4 = (float4*)P.cntc;
        for (int i = tid; i < CAP1; i += nT) c4[i] = zf;
        float4* a1 = (float4*)P.aggm1;
        for (int i = tid; i < CAP1 * 32; i += nT) a1[i] = zf;
        float4* a2 = (float4*)P.aggm2;
        for (int i = tid; i < P.G * 64; i += nT) a2[i] = zf;
    }
    grid.sync();

    // ================= phase A: mark last node per graph =================
    for (int g = tid; g < P.G; g += nT) {
        int bucket = g & (NB - 1);
        int last = P.ptr[g + 1] - 1;
        P.inv_map[last] = g;
        atomicOr(&P.bitL[last >> 5], 1u << (last & 31));
        atomicOr(&P.bitN1[last >> 5], 1u << (last & 31));
        claim_node(last, P.slot1, P.nodes1, P.ctr, 0, BC1, bucket);
        claim_node(last, P.slot0, P.nodes0, P.ctr, 1, BC0, bucket);
    }
    grid.sync();

    // ================= phase B: edges into last nodes =================
    {
        int bucket = (tid >> 6) & (NB - 1);
        int nC = (P.nE + 3) >> 2;
        for (int c = tid; c < nC; c += nT) {
            int e0 = c * 4;
            int d[4];
            int cnt = min(4, P.nE - e0);
            if (cnt == 4) { int4 v = *(const int4*)(P.dst + e0); d[0]=v.x; d[1]=v.y; d[2]=v.z; d[3]=v.w; }
            else for (int k = 0; k < cnt; k++) d[k] = P.dst[e0 + k];
#pragma unroll
            for (int k = 0; k < 4; k++) {
                if (k >= cnt) break;
                if (bittest(P.bitL, d[k])) {
                    int e = e0 + k;
                    int p = atomicAdd(&P.ctr[CTR(3, bucket)], 1);
                    if (p < BCE2) P.elist2[bucket * BCE2 + p] = e;
                    int s = P.src[e];
                    atomicOr(&P.bitN1[s >> 5], 1u << (s & 31));
                    claim_node(s, P.slot1, P.nodes1, P.ctr, 0, BC1, bucket);
                    claim_node(s, P.slot0, P.nodes0, P.ctr, 1, BC0, bucket);
                }
            }
        }
    }
    grid.sync();

    // ================= phase C: edges into need1 =================
    {
        int bucket = (tid >> 6) & (NB - 1);
        int nC = (P.nE + 3) >> 2;
        for (int c = tid; c < nC; c += nT) {
            int e0 = c * 4;
            int d[4];
            int cnt = min(4, P.nE - e0);
            if (cnt == 4) { int4 v = *(const int4*)(P.dst + e0); d[0]=v.x; d[1]=v.y; d[2]=v.z; d[3]=v.w; }
            else for (int k = 0; k < cnt; k++) d[k] = P.dst[e0 + k];
#pragma unroll
            for (int k = 0; k < 4; k++) {
                if (k >= cnt) break;
                if (bittest(P.bitN1, d[k])) {
                    int e = e0 + k;
                    int s1 = P.slot1[d[k]];
                    if (s1 >= 0) {
                        int p = atomicAdd(&P.ctr[CTR(2, bucket)], 1);
                        if (p < BCE1) P.elist1[bucket * BCE1 + p] = e;
                        atomicAdd(&P.cntc[s1 * 4 + P.et[e]], 1.0f);
                        claim_node(P.src[e], P.slot0, P.nodes0, P.ctr, 1, BC0, bucket);
                    }
                }
            }
        }
    }
    grid.sync();

    // ================= phase D: h0 = relu(embed @ pre_w + b) =================
    {
        if (t < 128) { smem[t] = P.se[t]; smem[128 + t] = P.ce[t]; }
        if (t < 32)  smem[768 + t] = P.pb[t];
        for (int i = t; i < 512; i += 256) smem[256 + i] = P.pw[i];
        __syncthreads();
        const float* s_se = smem;
        const float* s_ce = smem + 128;
        const float* s_pw = smem + 256;
        const float* s_pb = smem + 768;
        int lane = t & 63, f = lane & 31, half = lane >> 5;
        int wv = tid >> 6, nwv = nT >> 6;
        for (int idx = wv * 2 + half; idx < CAP0; idx += nwv * 2) {
            int b = idx >> 11, i = idx & (BC0 - 1);
            if (i >= min(P.ctr[CTR(1, b)], BC0)) continue;
            int n = P.nodes0[idx];
            int x0 = P.x[n * 2], x1 = P.x[n * 2 + 1];
            float acc = s_pb[f];
#pragma unroll
            for (int k = 0; k < 8; k++) acc += s_se[x0 * 8 + k] * s_pw[k * 32 + f];
#pragma unroll
            for (int k = 0; k < 8; k++) acc += s_ce[x1 * 8 + k] * s_pw[(k + 8) * 32 + f];
            P.h0c[(size_t)idx * 32 + f] = fmaxf(acc, 0.0f);
        }
    }
    grid.sync();

    // ================= phase E: accumulate raw h0 into per-(slot1,rel) =================
    {
        int lane = t & 63, f = lane & 31, half = lane >> 5;
        int wv = tid >> 6, nwv = nT >> 6;
        for (int idx = wv * 2 + half; idx < CAPE1; idx += nwv * 2) {
            int b = idx >> 10, i = idx & (BCE1 - 1);
            if (i >= min(P.ctr[CTR(2, b)], BCE1)) continue;
            int e = P.elist1[idx];
            int s0 = P.slot0[P.src[e]];
            int s1 = P.slot1[P.dst[e]];
            int r  = P.et[e];
            if (s0 < 0 || s1 < 0) continue;
            float v = P.h0c[(size_t)s0 * 32 + f];
            atomicAdd(&P.aggm1[((size_t)s1 * 4 + r) * 32 + f], v);
        }
    }
    grid.sync();

    // ================= phase F: h1 = relu(sum_r mean_r@W_r + h0@Wroot + b) =================
    {
        for (int i = t; i < NREL * 32 * 64; i += 256) smem[i] = P.w1r[i];
        for (int i = t; i < 32 * 64; i += 256) smem[6144 + i] = P.w1rt[i];
        if (t < 64) smem[8192 + t] = P.b1[t];
        __syncthreads();
        const float* s_w  = smem;
        const float* s_wr = smem + 6144;
        const float* s_b  = smem + 8192;
        int f = t & 63;
        int wv = tid >> 6, nwv = nT >> 6;
        for (int j = wv; j < CAP1; j += nwv) {
            int b = j >> 9, i = j & (BC1 - 1);
            if (i >= min(P.ctr[CTR(0, b)], BC1)) continue;
            int n = P.nodes1[j];
            int s0 = P.slot0[n];
            float acc = s_b[f];
            if (s0 >= 0) {
                const float4* h4 = (const float4*)(P.h0c + (size_t)s0 * 32);
#pragma unroll
                for (int k4 = 0; k4 < 8; k4++) {
                    float4 hv = h4[k4];
                    const float* wp = &s_wr[(k4 * 4) * 64 + f];
                    acc += hv.x * wp[0] + hv.y * wp[64] + hv.z * wp[128] + hv.w * wp[192];
                }
            }
#pragma unroll
            for (int r = 0; r < NREL; r++) {
                float ci = 1.0f / fmaxf(P.cntc[j * 4 + r], 1.0f);
                const float4* m4 = (const float4*)(P.aggm1 + ((size_t)j * 4 + r) * 32);
                float tmp = 0.0f;
#pragma unroll
                for (int k4 = 0; k4 < 8; k4++) {
                    float4 mv = m4[k4];
                    const float* wp = &s_w[r * 2048 + (k4 * 4) * 64 + f];
                    tmp += mv.x * wp[0] + mv.y * wp[64] + mv.z * wp[128] + mv.w * wp[192];
                }
                acc += tmp * ci;
            }
            P.h1c[(size_t)j * 64 + f] = fmaxf(acc, 0.0f);
        }
    }
    grid.sync();

    // ================= phase G: accumulate raw h1 into per-(graph,rel) =================
    {
        int f = t & 63;
        int wv = tid >> 6, nwv = nT >> 6;
        for (int idx = wv; idx < CAPE2; idx += nwv) {
            int b = idx >> 8, i = idx & (BCE2 - 1);
            if (i >= min(P.ctr[CTR(3, b)], BCE2)) continue;
            int e = P.elist2[idx];
            int ss = P.slot1[P.src[e]];
            int g  = P.inv_map[P.dst[e]];
            int r  = P.et[e];
            if (ss < 0 || g < 0) continue;
            float v = P.h1c[(size_t)ss * 64 + f];
            atomicAdd(&P.aggm2[((size_t)g * 4 + r) * 64 + f], v);
        }
    }
    grid.sync();

    // ================= phase H: layer-2 transform + classifier =================
    {
        for (int i = t; i < NREL * 64 * 64; i += 256) smem[i] = P.w2r[i];
        for (int i = t; i < 640; i += 256) smem[12288 + i] = P.cw[i];
        if (t < 10) smem[12928 + t] = P.cb[t];
        if (t < 64) smem[12944 + t] = P.b2[t];
        __syncthreads();
        const float* s_w  = smem;
        const float* s_cw = smem + 12288;
        const float* s_cb = smem + 12928;
        const float* s_b  = smem + 12944;
        float* s_h2 = smem + 13008;       // 256 floats (4 waves x 64)
        int wvl = t >> 6, f = t & 63;
        for (int base = blockIdx.x * 4; base < P.G; base += gridDim.x * 4) {
            int g = base + wvl;
            if (g < P.G) {
                int last = P.ptr[g + 1] - 1;
                int s1 = P.slot1[last];
                float acc = s_b[f];
                if (s1 >= 0) {
                    const float4* h4 = (const float4*)(P.h1c + (size_t)s1 * 64);
#pragma unroll
                    for (int k4 = 0; k4 < 16; k4++) {
                        float4 hv = h4[k4];
                        const float* wp = &P.w2rt[(k4 * 4) * 64 + f];   // L2-hot global
                        acc += hv.x * wp[0] + hv.y * wp[64] + hv.z * wp[128] + hv.w * wp[192];
                    }
#pragma unroll
                    for (int r = 0; r < NREL; r++) {
                        float ci = 1.0f / fmaxf(P.cntc[s1 * 4 + r], 1.0f);
                        const float4* m4 = (const float4*)(P.aggm2 + ((size_t)g * 4 + r) * 64);
                        float tmp = 0.0f;
#pragma unroll
                        for (int k4 = 0; k4 < 16; k4++) {
                            float4 mv = m4[k4];
                            const float* wp = &s_w[r * 4096 + (k4 * 4) * 64 + f];
                            tmp += mv.x * wp[0] + mv.y * wp[64] + mv.z * wp[128] + mv.w * wp[192];
                        }
                        acc += tmp * ci;
                    }
                }
                s_h2[wvl * 64 + f] = fmaxf(acc, 0.0f);
            }
            __syncthreads();
            if (g < P.G && f < 10) {
                float acc = s_cb[f];
#pragma unroll
                for (int k = 0; k < 64; k++) acc += s_h2[wvl * 64 + k] * s_cw[k * 10 + f];
                P.out[g * 10 + f] = acc;
            }
            __syncthreads();
        }
    }
}

static inline size_t rnd(size_t x) { return (x + 255) & ~(size_t)255; }

extern "C" void kernel_launch(void* const* d_in, const int* in_sizes, int n_in,
                              void* d_out, int out_size, void* d_ws, size_t ws_size,
                              hipStream_t stream) {
    Params P;
    P.x    = (const int*)d_in[0];
    const int* ei = (const int*)d_in[1];
    P.et   = (const int*)d_in[2];
    P.ptr  = (const int*)d_in[3];
    P.se   = (const float*)d_in[4];
    P.ce   = (const float*)d_in[5];
    P.pw   = (const float*)d_in[6];
    P.pb   = (const float*)d_in[7];
    P.w1r  = (const float*)d_in[8];
    P.w1rt = (const float*)d_in[9];
    P.b1   = (const float*)d_in[10];
    P.w2r  = (const float*)d_in[11];
    P.w2rt = (const float*)d_in[12];
    P.b2   = (const float*)d_in[13];
    P.cw   = (const float*)d_in[14];
    P.cb   = (const float*)d_in[15];
    P.out  = (float*)d_out;

    P.nN = in_sizes[0] / 2;          // 500000
    P.nE = in_sizes[2];              // 1000000
    P.G  = in_sizes[3] - 1;          // 5000
    P.nBW = (P.nN + 31) / 32;
    P.src = ei;
    P.dst = ei + P.nE;

    char* p = (char*)d_ws;
    size_t off = 0;
    auto take = [&](size_t bytes) { size_t o = off; off += rnd(bytes); return o; };

    P.ctr    = (int*)     (p + take(4 * NB * CS * sizeof(int)));
    P.bitL   = (unsigned*)(p + take((size_t)P.nBW * 4));
    P.bitN1  = (unsigned*)(p + take((size_t)P.nBW * 4));
    P.cntc   = (float*)   (p + take((size_t)CAP1 * 4 * 4));
    P.aggm1  = (float*)   (p + take((size_t)CAP1 * 4 * 32 * 4));   // 16 MB
    P.aggm2  = (float*)   (p + take((size_t)P.G * 4 * 64 * 4));    // 5 MB
    P.inv_map= (int*)     (p + take((size_t)P.nN * 4));
    P.slot1  = (int*)     (p + take((size_t)P.nN * 4));
    P.slot0  = (int*)     (p + take((size_t)P.nN * 4));
    P.elist1 = (int*)     (p + take((size_t)CAPE1 * 4));
    P.elist2 = (int*)     (p + take((size_t)CAPE2 * 4));
    P.nodes1 = (int*)     (p + take((size_t)CAP1 * 4));
    P.nodes0 = (int*)     (p + take((size_t)CAP0 * 4));
    P.h0c    = (float*)   (p + take((size_t)CAP0 * 32 * 4));       // 16 MB
    P.h1c    = (float*)   (p + take((size_t)CAP1 * 64 * 4));       // 8 MB
    // total ~53 MB; all init done in-kernel (phase 0)

    // cooperative grid: exactly max-resident blocks (grid-stride phases are
    // correct for any grid size; residency is required for grid.sync)
    int dev = 0;
    (void)hipGetDevice(&dev);
    int nCU = 256;
    (void)hipDeviceGetAttribute(&nCU, hipDeviceAttributeMultiprocessorCount, dev);
    int maxB = 0;
    (void)hipOccupancyMaxActiveBlocksPerMultiprocessor(&maxB, fused_k, 256, 0);
    if (maxB < 1) maxB = 1;
    long long grid = (long long)maxB * nCU;
    if (grid > 2048) grid = 2048;

    void* args[] = { &P };
    (void)hipLaunchCooperativeKernel((void*)fused_k, dim3((unsigned)grid), dim3(256),
                                     args, 0, stream);
}